// Round 2
// baseline (122.187 us; speedup 1.0000x reference)
//
#include <hip/hip_runtime.h>

// N=32, C=96, H=W=56. HW=3136, NP=100352.
// d_out = [ out (9,633,792 f32) | fmap (9,633,792 f32) ]

#define HW 3136
#define CC 96
#define NB 32

// ---------------------------------------------------------------------------
// K1: fmap = conv1x1_g2( bnrelu1( concat(x0, f1, x1, f0) ), w1 )
// grid = 392 (196 pixel-tiles x 2 groups); block = 256 (4 waves); 2 px/thread
// -> 512 px per block. Weights (96ci x 48o = 18KB) + BN params staged in LDS.
// ---------------------------------------------------------------------------
__global__ __launch_bounds__(256) void k1_conv1(
    const float* __restrict__ x, const float* __restrict__ prev,
    const float* __restrict__ g1, const float* __restrict__ be1,
    const float* __restrict__ m1, const float* __restrict__ v1,
    const float* __restrict__ w1, float* __restrict__ fmap) {
  __shared__ float lw[96 * 48];   // lw[ci*48+o] = w1[(g*48+o)*96+ci]
  __shared__ float ls[96], lb[96];

  const int tid = threadIdx.x;
  const int g = blockIdx.x & 1;
  const int tile = blockIdx.x >> 1;

  for (int t = tid; t < 96 * 48; t += 256) {
    int ci = t / 48, o = t - ci * 48;
    lw[t] = w1[(g * 48 + o) * 96 + ci];
  }
  if (tid < 96) {
    int cg = g * 96 + tid;
    float s = g1[cg] / sqrtf(v1[cg] + 1e-5f);
    ls[tid] = s;
    lb[tid] = be1[cg] - m1[cg] * s;
  }
  __syncthreads();

  const int wv = tid >> 6, lane = tid & 63;
  const int px0 = tile * 512 + wv * 128 + lane;  // px1 = px0 + 64
  const int n0 = px0 / HW, p0 = px0 - n0 * HW;
  const int px1 = px0 + 64;
  const int n1 = px1 / HW, p1 = px1 - n1 * HW;

  const int base0 = n0 * CC * HW + p0;
  const int base1 = n1 * CC * HW + p1;

  // group0: A = x[0:48], B = prev[48:96]; group1: A = x[48:96], B = prev[0:48]
  const float* A0 = x + base0 + (g ? 48 * HW : 0);
  const float* A1 = x + base1 + (g ? 48 * HW : 0);
  const float* B0 = prev + base0 + (g ? 0 : 48 * HW);
  const float* B1 = prev + base1 + (g ? 0 : 48 * HW);

  float acc0[48], acc1[48];
#pragma unroll
  for (int o = 0; o < 48; ++o) { acc0[o] = 0.f; acc1[o] = 0.f; }

  for (int ci = 0; ci < 48; ++ci) {
    float s = ls[ci], b = lb[ci];
    float va = fmaxf(fmaf(A0[ci * HW], s, b), 0.f);
    float vb = fmaxf(fmaf(A1[ci * HW], s, b), 0.f);
    const float* wr = &lw[ci * 48];
#pragma unroll
    for (int o = 0; o < 48; ++o) {
      float w = wr[o];
      acc0[o] = fmaf(w, va, acc0[o]);
      acc1[o] = fmaf(w, vb, acc1[o]);
    }
  }
  for (int ci = 48; ci < 96; ++ci) {
    float s = ls[ci], b = lb[ci];
    float va = fmaxf(fmaf(B0[(ci - 48) * HW], s, b), 0.f);
    float vb = fmaxf(fmaf(B1[(ci - 48) * HW], s, b), 0.f);
    const float* wr = &lw[ci * 48];
#pragma unroll
    for (int o = 0; o < 48; ++o) {
      float w = wr[o];
      acc0[o] = fmaf(w, va, acc0[o]);
      acc1[o] = fmaf(w, vb, acc1[o]);
    }
  }

  float* F0 = fmap + base0 + g * 48 * HW;
  float* F1 = fmap + base1 + g * 48 * HW;
#pragma unroll
  for (int o = 0; o < 48; ++o) {
    F0[o * HW] = acc0[o];
    F1[o * HW] = acc1[o];
  }
}

// ---------------------------------------------------------------------------
// K2: out = conv1x1_g3( active_shift( bnrelu2(fmap) ), w2 ) + x
// grid = 784; block = 192 (3 waves, one group each); 2 px/thread -> 128 px/blk.
// Per-channel {s,b,w00,w01,w10,w11,ay,ax} + weights (12KB) staged in LDS.
// Shift in (-1,1) => taps at {t, t+1, t+56, t+57}, t = p + ay*56 + ax.
// ---------------------------------------------------------------------------
__global__ __launch_bounds__(192) void k2_shift_conv2(
    const float* __restrict__ x, const float* __restrict__ fmap,
    const float* __restrict__ g2, const float* __restrict__ be2,
    const float* __restrict__ m2, const float* __restrict__ v2,
    const float* __restrict__ w2, const float* __restrict__ shift,
    float* __restrict__ out) {
  __shared__ float lw[96 * 32];   // lw[c*32+o] = w2[((c>>5)*32+o)*32 + (c&31)]
  __shared__ float prm[96][8];

  const int tid = threadIdx.x;
  for (int t = tid; t < 96 * 32; t += 192) {
    int c = t >> 5, o = t & 31;
    lw[t] = w2[((c >> 5) * 32 + o) * 32 + (c & 31)];
  }
  if (tid < 96) {
    int c = tid;
    float s = g2[c] / sqrtf(v2[c] + 1e-5f);
    float b = be2[c] - m2[c] * s;
    float dy = shift[2 * c], dx = shift[2 * c + 1];
    float fy = floorf(dy), fx = floorf(dx);
    float wy = dy - fy, wx = dx - fx;
    prm[c][0] = s;
    prm[c][1] = b;
    prm[c][2] = (1.f - wy) * (1.f - wx);
    prm[c][3] = (1.f - wy) * wx;
    prm[c][4] = wy * (1.f - wx);
    prm[c][5] = wy * wx;
    prm[c][6] = __int_as_float((int)fy);
    prm[c][7] = __int_as_float((int)fx);
  }
  __syncthreads();

  const int G = tid >> 6;          // group 0..2
  const int lane = tid & 63;
  const int px0 = blockIdx.x * 128 + lane;
  const int px1 = px0 + 64;
  const int n0 = px0 / HW, p0 = px0 - n0 * HW;
  const int n1 = px1 / HW, p1 = px1 - n1 * HW;
  const int y0 = p0 / 56, x0c = p0 - y0 * 56;
  const int y1 = p1 / 56, x1c = p1 - y1 * 56;

  const float* fb0 = fmap + (n0 * CC + G * 32) * HW;
  const float* fb1 = fmap + (n1 * CC + G * 32) * HW;

  float acc0[32], acc1[32];
#pragma unroll
  for (int o = 0; o < 32; ++o) { acc0[o] = 0.f; acc1[o] = 0.f; }

  for (int ci = 0; ci < 32; ++ci) {
    const int c = G * 32 + ci;
    const float s = prm[c][0], b = prm[c][1];
    const float w00 = prm[c][2], w01 = prm[c][3];
    const float w10 = prm[c][4], w11 = prm[c][5];
    const int ay = __float_as_int(prm[c][6]);
    const int ax = __float_as_int(prm[c][7]);
    const int off = ay * 56 + ax;
    const float* fc0 = fb0 + ci * HW;
    const float* fc1 = fb1 + ci * HW;

    float h0, h1;
    {
      const int yq = y0 + ay, xq = x0c + ax;
      const int t = p0 + off;
      float f00 = fc0[min(max(t, 0), HW - 1)];
      float f01 = fc0[min(max(t + 1, 0), HW - 1)];
      float f10 = fc0[min(max(t + 56, 0), HW - 1)];
      float f11 = fc0[min(max(t + 57, 0), HW - 1)];
      float q00 = fmaxf(fmaf(f00, s, b), 0.f);
      float q01 = fmaxf(fmaf(f01, s, b), 0.f);
      float q10 = fmaxf(fmaf(f10, s, b), 0.f);
      float q11 = fmaxf(fmaf(f11, s, b), 0.f);
      const bool vy0 = yq >= 0, vy1 = yq <= 54;
      const bool vx0 = xq >= 0, vx1 = xq <= 54;
      h0 = ((vy0 && vx0) ? w00 : 0.f) * q00;
      h0 = fmaf(((vy0 && vx1) ? w01 : 0.f), q01, h0);
      h0 = fmaf(((vy1 && vx0) ? w10 : 0.f), q10, h0);
      h0 = fmaf(((vy1 && vx1) ? w11 : 0.f), q11, h0);
    }
    {
      const int yq = y1 + ay, xq = x1c + ax;
      const int t = p1 + off;
      float f00 = fc1[min(max(t, 0), HW - 1)];
      float f01 = fc1[min(max(t + 1, 0), HW - 1)];
      float f10 = fc1[min(max(t + 56, 0), HW - 1)];
      float f11 = fc1[min(max(t + 57, 0), HW - 1)];
      float q00 = fmaxf(fmaf(f00, s, b), 0.f);
      float q01 = fmaxf(fmaf(f01, s, b), 0.f);
      float q10 = fmaxf(fmaf(f10, s, b), 0.f);
      float q11 = fmaxf(fmaf(f11, s, b), 0.f);
      const bool vy0 = yq >= 0, vy1 = yq <= 54;
      const bool vx0 = xq >= 0, vx1 = xq <= 54;
      h1 = ((vy0 && vx0) ? w00 : 0.f) * q00;
      h1 = fmaf(((vy0 && vx1) ? w01 : 0.f), q01, h1);
      h1 = fmaf(((vy1 && vx0) ? w10 : 0.f), q10, h1);
      h1 = fmaf(((vy1 && vx1) ? w11 : 0.f), q11, h1);
    }

    const float* wr = &lw[c * 32];
#pragma unroll
    for (int o = 0; o < 32; ++o) {
      float w = wr[o];
      acc0[o] = fmaf(w, h0, acc0[o]);
      acc1[o] = fmaf(w, h1, acc1[o]);
    }
  }

  const int ob0 = (n0 * CC + G * 32) * HW + p0;
  const int ob1 = (n1 * CC + G * 32) * HW + p1;
#pragma unroll
  for (int o = 0; o < 32; ++o) {
    out[ob0 + o * HW] = acc0[o] + x[ob0 + o * HW];
    out[ob1 + o * HW] = acc1[o] + x[ob1 + o * HW];
  }
}

extern "C" void kernel_launch(void* const* d_in, const int* in_sizes, int n_in,
                              void* d_out, int out_size, void* d_ws, size_t ws_size,
                              hipStream_t stream) {
  const float* x     = (const float*)d_in[0];
  const float* prev  = (const float*)d_in[1];
  const float* g1    = (const float*)d_in[2];
  const float* be1   = (const float*)d_in[3];
  const float* m1    = (const float*)d_in[4];
  const float* v1    = (const float*)d_in[5];
  const float* g2    = (const float*)d_in[6];
  const float* be2   = (const float*)d_in[7];
  const float* m2    = (const float*)d_in[8];
  const float* v2    = (const float*)d_in[9];
  const float* w1    = (const float*)d_in[10];
  const float* w2    = (const float*)d_in[11];
  const float* shift = (const float*)d_in[12];

  float* out  = (float*)d_out;
  float* fmap = out + (size_t)NB * CC * HW;  // second output, written in place

  k1_conv1<<<392, 256, 0, stream>>>(x, prev, g1, be1, m1, v1, w1, fmap);
  k2_shift_conv2<<<784, 192, 0, stream>>>(x, fmap, g2, be2, m2, v2, w2, shift,
                                          out);
}

// Round 3
// 110.492 us; speedup vs baseline: 1.1058x; 1.1058x over previous
//
#include <hip/hip_runtime.h>

// N=32, C=96, H=W=56. HW=3136, NP=100352.
// d_out = [ out (9,633,792 f32) | fmap (9,633,792 f32) ]
//
// ws layout (float index):
//   [    0, 9216) w1t[(g*96+ci)*48 + o] = w1[(g*48+o)*96 + ci]
//   [ 9216, 9408) s1[192]
//   [ 9408, 9600) b1[192]

#define WS_W1T 0
#define WS_S1  9216
#define WS_B1  9408

#define HW 3136
#define CC 96
#define NB 32

__global__ __launch_bounds__(256) void precompute_k(
    const float* __restrict__ g1, const float* __restrict__ be1,
    const float* __restrict__ m1, const float* __restrict__ v1,
    const float* __restrict__ w1, float* __restrict__ ws) {
  const int tid = threadIdx.x;
  for (int i = tid; i < 9216; i += 256) {
    int gci = i / 48, o = i - gci * 48;
    int g = gci / 96, ci = gci - g * 96;
    ws[WS_W1T + i] = w1[(g * 48 + o) * 96 + ci];
  }
  if (tid < 192) {
    float s = g1[tid] / sqrtf(v1[tid] + 1e-5f);
    ws[WS_S1 + tid] = s;
    ws[WS_B1 + tid] = be1[tid] - m1[tid] * s;
  }
}

// ---------------------------------------------------------------------------
// K1: fmap = conv1x1_g2( bnrelu1( concat(x0, f1, x1, f0) ), w1 )
// grid = 784; block = 256 = 4 waves: wave = (g, out-half). Each thread:
// 2 px x 24 outs = 48 accs. Weights/BN via uniform s_load from ws.
// Acts prefetched with a depth-4 register ring.
// ---------------------------------------------------------------------------
__global__ __launch_bounds__(256) void k1_conv1(
    const float* __restrict__ x, const float* __restrict__ prev,
    const float* __restrict__ ws, float* __restrict__ fmap) {
  const int tid = threadIdx.x;
  const int lane = tid & 63;
  const int wv = tid >> 6;
  const int g = __builtin_amdgcn_readfirstlane(wv >> 1);
  const int h = __builtin_amdgcn_readfirstlane(wv & 1);  // out-half

  const int px0 = blockIdx.x * 128 + lane;
  const int px1 = px0 + 64;
  const int n0 = px0 / HW, p0 = px0 - n0 * HW;
  const int n1 = px1 / HW, p1 = px1 - n1 * HW;
  const int base0 = n0 * CC * HW + p0;
  const int base1 = n1 * CC * HW + p1;

  // ci in [0,48): from x (+48*HW if g==1); ci in [48,96): from prev,
  // pre-biased by -48*HW so both index as ptr[ci*HW].
  const float* PA0 = x + base0 + (g ? 48 * HW : 0);
  const float* PA1 = x + base1 + (g ? 48 * HW : 0);
  const float* PB0 = prev + base0 + (g ? -48 * HW : 0);
  const float* PB1 = prev + base1 + (g ? -48 * HW : 0);

  const float* sp = ws + WS_S1 + g * 96;
  const float* bp = ws + WS_B1 + g * 96;
  const float* wt = ws + WS_W1T + g * 96 * 48 + h * 24;  // row stride 48

  float acc0[24], acc1[24];
#pragma unroll
  for (int o = 0; o < 24; ++o) { acc0[o] = 0.f; acc1[o] = 0.f; }

  float buf0[4], buf1[4];
#pragma unroll
  for (int k = 0; k < 4; ++k) {
    buf0[k] = PA0[k * HW];
    buf1[k] = PA1[k * HW];
  }

#pragma unroll 4
  for (int ci = 0; ci < 96; ++ci) {
    const float c0 = buf0[ci & 3];
    const float c1 = buf1[ci & 3];
    const int nx = ci + 4;
    if (nx < 96) {
      const float* q0 = (nx < 48) ? PA0 : PB0;
      const float* q1 = (nx < 48) ? PA1 : PB1;
      buf0[ci & 3] = q0[nx * HW];
      buf1[ci & 3] = q1[nx * HW];
    }
    const float s = sp[ci], b = bp[ci];
    const float a0 = fmaxf(fmaf(c0, s, b), 0.f);
    const float a1 = fmaxf(fmaf(c1, s, b), 0.f);
    const float* wr = wt + ci * 48;
#pragma unroll
    for (int o = 0; o < 24; ++o) {
      const float w = wr[o];
      acc0[o] = fmaf(w, a0, acc0[o]);
      acc1[o] = fmaf(w, a1, acc1[o]);
    }
  }

  float* F0 = fmap + base0 + (g * 48 + h * 24) * HW;
  float* F1 = fmap + base1 + (g * 48 + h * 24) * HW;
#pragma unroll
  for (int o = 0; o < 24; ++o) {
    F0[o * HW] = acc0[o];
    F1[o * HW] = acc1[o];
  }
}

// ---------------------------------------------------------------------------
// K2: out = conv1x1_g3( active_shift( bnrelu2(fmap) ), w2 ) + x
// (unchanged from round 2 — measured ~9 us)
// ---------------------------------------------------------------------------
__global__ __launch_bounds__(192) void k2_shift_conv2(
    const float* __restrict__ x, const float* __restrict__ fmap,
    const float* __restrict__ g2, const float* __restrict__ be2,
    const float* __restrict__ m2, const float* __restrict__ v2,
    const float* __restrict__ w2, const float* __restrict__ shift,
    float* __restrict__ out) {
  __shared__ float lw[96 * 32];   // lw[c*32+o] = w2[((c>>5)*32+o)*32 + (c&31)]
  __shared__ float prm[96][8];

  const int tid = threadIdx.x;
  for (int t = tid; t < 96 * 32; t += 192) {
    int c = t >> 5, o = t & 31;
    lw[t] = w2[((c >> 5) * 32 + o) * 32 + (c & 31)];
  }
  if (tid < 96) {
    int c = tid;
    float s = g2[c] / sqrtf(v2[c] + 1e-5f);
    float b = be2[c] - m2[c] * s;
    float dy = shift[2 * c], dx = shift[2 * c + 1];
    float fy = floorf(dy), fx = floorf(dx);
    float wy = dy - fy, wx = dx - fx;
    prm[c][0] = s;
    prm[c][1] = b;
    prm[c][2] = (1.f - wy) * (1.f - wx);
    prm[c][3] = (1.f - wy) * wx;
    prm[c][4] = wy * (1.f - wx);
    prm[c][5] = wy * wx;
    prm[c][6] = __int_as_float((int)fy);
    prm[c][7] = __int_as_float((int)fx);
  }
  __syncthreads();

  const int G = tid >> 6;          // group 0..2
  const int lane = tid & 63;
  const int px0 = blockIdx.x * 128 + lane;
  const int px1 = px0 + 64;
  const int n0 = px0 / HW, p0 = px0 - n0 * HW;
  const int n1 = px1 / HW, p1 = px1 - n1 * HW;
  const int y0 = p0 / 56, x0c = p0 - y0 * 56;
  const int y1 = p1 / 56, x1c = p1 - y1 * 56;

  const float* fb0 = fmap + (n0 * CC + G * 32) * HW;
  const float* fb1 = fmap + (n1 * CC + G * 32) * HW;

  float acc0[32], acc1[32];
#pragma unroll
  for (int o = 0; o < 32; ++o) { acc0[o] = 0.f; acc1[o] = 0.f; }

  for (int ci = 0; ci < 32; ++ci) {
    const int c = G * 32 + ci;
    const float s = prm[c][0], b = prm[c][1];
    const float w00 = prm[c][2], w01 = prm[c][3];
    const float w10 = prm[c][4], w11 = prm[c][5];
    const int ay = __float_as_int(prm[c][6]);
    const int ax = __float_as_int(prm[c][7]);
    const int off = ay * 56 + ax;
    const float* fc0 = fb0 + ci * HW;
    const float* fc1 = fb1 + ci * HW;

    float h0, h1;
    {
      const int yq = y0 + ay, xq = x0c + ax;
      const int t = p0 + off;
      float f00 = fc0[min(max(t, 0), HW - 1)];
      float f01 = fc0[min(max(t + 1, 0), HW - 1)];
      float f10 = fc0[min(max(t + 56, 0), HW - 1)];
      float f11 = fc0[min(max(t + 57, 0), HW - 1)];
      float q00 = fmaxf(fmaf(f00, s, b), 0.f);
      float q01 = fmaxf(fmaf(f01, s, b), 0.f);
      float q10 = fmaxf(fmaf(f10, s, b), 0.f);
      float q11 = fmaxf(fmaf(f11, s, b), 0.f);
      const bool vy0 = yq >= 0, vy1 = yq <= 54;
      const bool vx0 = xq >= 0, vx1 = xq <= 54;
      h0 = ((vy0 && vx0) ? w00 : 0.f) * q00;
      h0 = fmaf(((vy0 && vx1) ? w01 : 0.f), q01, h0);
      h0 = fmaf(((vy1 && vx0) ? w10 : 0.f), q10, h0);
      h0 = fmaf(((vy1 && vx1) ? w11 : 0.f), q11, h0);
    }
    {
      const int yq = y1 + ay, xq = x1c + ax;
      const int t = p1 + off;
      float f00 = fc1[min(max(t, 0), HW - 1)];
      float f01 = fc1[min(max(t + 1, 0), HW - 1)];
      float f10 = fc1[min(max(t + 56, 0), HW - 1)];
      float f11 = fc1[min(max(t + 57, 0), HW - 1)];
      float q00 = fmaxf(fmaf(f00, s, b), 0.f);
      float q01 = fmaxf(fmaf(f01, s, b), 0.f);
      float q10 = fmaxf(fmaf(f10, s, b), 0.f);
      float q11 = fmaxf(fmaf(f11, s, b), 0.f);
      const bool vy0 = yq >= 0, vy1 = yq <= 54;
      const bool vx0 = xq >= 0, vx1 = xq <= 54;
      h1 = ((vy0 && vx0) ? w00 : 0.f) * q00;
      h1 = fmaf(((vy0 && vx1) ? w01 : 0.f), q01, h1);
      h1 = fmaf(((vy1 && vx0) ? w10 : 0.f), q10, h1);
      h1 = fmaf(((vy1 && vx1) ? w11 : 0.f), q11, h1);
    }

    const float* wr = &lw[c * 32];
#pragma unroll
    for (int o = 0; o < 32; ++o) {
      float w = wr[o];
      acc0[o] = fmaf(w, h0, acc0[o]);
      acc1[o] = fmaf(w, h1, acc1[o]);
    }
  }

  const int ob0 = (n0 * CC + G * 32) * HW + p0;
  const int ob1 = (n1 * CC + G * 32) * HW + p1;
#pragma unroll
  for (int o = 0; o < 32; ++o) {
    out[ob0 + o * HW] = acc0[o] + x[ob0 + o * HW];
    out[ob1 + o * HW] = acc1[o] + x[ob1 + o * HW];
  }
}

extern "C" void kernel_launch(void* const* d_in, const int* in_sizes, int n_in,
                              void* d_out, int out_size, void* d_ws, size_t ws_size,
                              hipStream_t stream) {
  const float* x     = (const float*)d_in[0];
  const float* prev  = (const float*)d_in[1];
  const float* g1    = (const float*)d_in[2];
  const float* be1   = (const float*)d_in[3];
  const float* m1    = (const float*)d_in[4];
  const float* v1    = (const float*)d_in[5];
  const float* g2    = (const float*)d_in[6];
  const float* be2   = (const float*)d_in[7];
  const float* m2    = (const float*)d_in[8];
  const float* v2    = (const float*)d_in[9];
  const float* w1    = (const float*)d_in[10];
  const float* w2    = (const float*)d_in[11];
  const float* shift = (const float*)d_in[12];

  float* out  = (float*)d_out;
  float* fmap = out + (size_t)NB * CC * HW;  // second output, written in place
  float* ws   = (float*)d_ws;

  precompute_k<<<1, 256, 0, stream>>>(g1, be1, m1, v1, w1, ws);
  k1_conv1<<<784, 256, 0, stream>>>(x, prev, ws, fmap);
  k2_shift_conv2<<<784, 192, 0, stream>>>(x, fmap, g2, be2, m2, v2, w2, shift,
                                          out);
}